// Round 9
// baseline (127.961 us; speedup 1.0000x reference)
//
#include <hip/hip_runtime.h>
#include <hip/hip_bf16.h>

#define BATCH 65536

typedef __bf16 bf16_t;
typedef __bf16 bf16x8 __attribute__((ext_vector_type(8)));
typedef float  f32x4  __attribute__((ext_vector_type(4)));

__device__ __forceinline__ f32x4 mfma16(bf16x8 a, bf16x8 b, f32x4 c) {
    return __builtin_amdgcn_mfma_f32_16x16x32_bf16(a, b, c, 0, 0, 0);
}
// element index into a 128-col bf16 LDS tile, XOR-swizzled on 16B chunks
__device__ __forceinline__ int swz128(int row, int col) {
    return row * 128 + ((((col >> 3) ^ (row & 7)) << 3) | (col & 7));
}

// ---------------------------------------------------------------------------
// Weight prep: f32 weights -> pre-swizzled bf16 B-fragments.
// Fragment (nt,kt): lane l elem j holds W[32*kt + 8*(l>>4) + j][16*nt + (l&15)]
// at dst[fragIdx*512 + l*8 + j].
// Frag map (368 frags):
//   0   c1_W12 = c1_rw1@c1_rw2 (128x128, 32)
//   32  c1_kwd (c1_kw rows 0..127, 32)     64  c1_kws (rows 128..255, 32)
//   96  c2_W12 (32)   128 c2_kwd (32)   160 c2_kws (32)
//   192 fc3 (128x32, 8)   200 fc4 (8)   208 fc5 (32x128 K=32, 8)
//   216 d1_mw (32)  248 d1_rw (32)  280 d2_mw (128x78, 20)  300 d2_rw (20)
//   320 c0_W12 = c0_rw1@c0_rw2 (K pad 4->32, 8)
//   328 c0_kw dst rows 0..3 (8)   336 c0_kw src rows 4..7 (8)
//   344 c0_kwe rows 8..12 (8)  352 c1_kwe rows 256..260 (8)  360 c2_kwe (8)
// bias: [0:128) b12_c1 | [128:256) b12_c2 | [256:384) b0_c0
// ---------------------------------------------------------------------------
struct PrepSrcs { const float* p[16]; };

__global__ __launch_bounds__(256) void prep_weights(PrepSrcs ps,
    const float* __restrict__ c0_rb1, const float* __restrict__ c0_rb2,
    const float* __restrict__ c1_rb1, const float* __restrict__ c1_rb2,
    const float* __restrict__ c2_rb1, const float* __restrict__ c2_rb2,
    bf16_t* __restrict__ dst, float* __restrict__ bias)
{
    int f = blockIdx.x;
    if (f >= 368) {                       // bias blocks
        int c = threadIdx.x;
        if (c < 128) {
            if (f == 368) {               // b12_c1 = c1_rb1 @ c1_rw2 + c1_rb2
                const float* rw2 = ps.p[11];
                float s = c1_rb2[c];
                for (int m = 0; m < 128; m++) s += c1_rb1[m] * rw2[m * 128 + c];
                bias[c] = s;
            } else if (f == 369) {        // b12_c2
                const float* rw2 = ps.p[13];
                float s = c2_rb2[c];
                for (int m = 0; m < 128; m++) s += c2_rb1[m] * rw2[m * 128 + c];
                bias[128 + c] = s;
            } else {                      // b0 = c0_rb1 @ c0_rw2 + c0_rb2
                const float* rw2 = ps.p[15];
                float s = c0_rb2[c];
                for (int m = 0; m < 4; m++) s += c0_rb1[m] * rw2[m * 128 + c];
                bias[256 + c] = s;
            }
        }
        return;
    }
    const int BASE[20] = {0,32,64,96,128,160,192,200,208,216,248,280,300,320,328,336,344,352,360,368};
    const int SRC[19]  = {10,0,0,12,1,1,2,3,4,5,6,7,8,14,9,9,9,0,1};
    const int KTt[19]  = {4,4,4,4,4,4,4,4,1,4,4,4,4,1,1,1,1,1,1};
    const int KLIM[19] = {128,128,128,128,128,128,128,128,32,128,128,128,128,4,4,4,5,5,5};
    const int NLIM[19] = {128,128,128,128,128,128,32,32,128,128,128,78,78,128,128,128,128,128,128};
    const int STR[19]  = {128,128,128,128,128,128,32,32,128,128,128,78,78,128,128,128,128,128,128};
    const int RO[19]   = {0,0,128,0,0,128,0,0,0,0,0,0,0,0,0,4,8,256,256};

    int ei = 0;
    while (ei < 18 && BASE[ei + 1] <= f) ei++;
    int lf = f - BASE[ei];
    int kt = lf % KTt[ei];
    int nt = lf / KTt[ei];
    #pragma unroll
    for (int r2 = 0; r2 < 2; r2++) {
        int idx = threadIdx.x * 2 + r2;
        int l = idx >> 3, j = idx & 7;
        int row = 32 * kt + 8 * (l >> 4) + j;
        int col = 16 * nt + (l & 15);
        float v = 0.f;
        if (ei == 0 || ei == 3) {         // W12 = rw1 @ rw2, K=128
            const float* rw1 = ps.p[ei == 0 ? 10 : 12];
            const float* rw2 = ps.p[ei == 0 ? 11 : 13];
            for (int m = 0; m < 128; m++) v += rw1[row * 128 + m] * rw2[m * 128 + col];
        } else if (ei == 13) {            // c0_W12, K=4 (rows >=4 zero)
            if (row < 4) {
                const float* rw1 = ps.p[14];
                const float* rw2 = ps.p[15];
                for (int m = 0; m < 4; m++) v += rw1[row * 4 + m] * rw2[m * 128 + col];
            }
        } else {
            if (row < KLIM[ei] && col < NLIM[ei])
                v = ps.p[SRC[ei]][(row + RO[ei]) * STR[ei] + col];
        }
        dst[f * 512 + idx] = (bf16_t)v;
    }
}

// ---------------------------------------------------------------------------
// Per-lane message assembly. edges: src {0,0,1,0,1,2} dst {1,2,2,3,3,3}
// ---------------------------------------------------------------------------
__device__ __forceinline__ void edge_update(float o[4], const f32x4& kd, const f32x4& ks,
                                            const float* et)
{
    float mm;
    mm = kd[1] + ks[0] + et[0]; mm = fmaxf(mm, 0.01f * mm); o[1] += mm;
    mm = kd[2] + ks[0] + et[1]; mm = fmaxf(mm, 0.01f * mm); o[2] += mm;
    mm = kd[2] + ks[1] + et[2]; mm = fmaxf(mm, 0.01f * mm); o[2] += mm;
    mm = kd[3] + ks[0] + et[3]; mm = fmaxf(mm, 0.01f * mm); o[3] += mm;
    mm = kd[3] + ks[1] + et[4]; mm = fmaxf(mm, 0.01f * mm); o[3] += mm;
    mm = kd[3] + ks[2] + et[5]; mm = fmaxf(mm, 0.01f * mm); o[3] += mm;
}

// ---------------------------------------------------------------------------
// et via lane-local MFMA output (no LDS round-trip).
// A-row permutation chosen so C rows land in the consuming lane:
//   aet[0] (mt=0) / aet[1] (mt=1): row 4*q_el + u  -> lane q_el, reg u   (u=0..3)
//   aet[2] (both mt):  row 4*q_el + 2*mt_el + (u-4) -> lane q_el, reg 2*mt+(u-4)
// ---------------------------------------------------------------------------

// ---------------------------------------------------------------------------
// Single-pass conv layer (resid collapsed into W12): out = h@W12 + b12 + msgs.
// LAST: write hg (sum of 4 node rows) into lA rows 0..31.
// ---------------------------------------------------------------------------
template<bool LAST>
__device__ __forceinline__ void conv_pass(
    bf16_t* lA, const bf16x8 aet[3],
    const bf16_t* wf, const bf16_t* wet, const float* b12,
    int w, int q, int lr, int lane)
{
    bf16x8 ah[2][4];
    #pragma unroll
    for (int mt = 0; mt < 2; mt++) {
        int row = 32 * w + 16 * mt + lr;
        #pragma unroll
        for (int kt = 0; kt < 4; kt++)
            ah[mt][kt] = *(const bf16x8*)(lA + row * 128 + (((4 * kt + q) ^ (row & 7)) << 3));
    }
    // preload all 8 bias values (removes dependent global load from loop body)
    float bv8[8];
    #pragma unroll
    for (int nt = 0; nt < 8; nt++) bv8[nt] = b12[16 * nt + lr];
    __syncthreads();                      // all reads done; lA may be overwritten

    const bf16_t* wfd = wf + 32 * 512;
    const bf16_t* wfs = wf + 64 * 512;
    #pragma unroll 2
    for (int nt = 0; nt < 8; nt++) {
        int col = 16 * nt + lr;
        const f32x4 zz = {0.f, 0.f, 0.f, 0.f};
        bf16x8 be = *(const bf16x8*)(wet + nt * 512 + lane * 8);
        f32x4 zet0 = mfma16(aet[0], be, zz);
        f32x4 zet1 = mfma16(aet[1], be, zz);
        f32x4 zetB = mfma16(aet[2], be, zz);
        float bv = bv8[nt];
        f32x4 rr[2], kd[2], ks[2];
        rr[0] = (f32x4){bv, bv, bv, bv}; rr[1] = rr[0];
        kd[0] = zz; kd[1] = zz;
        ks[0] = zz; ks[1] = zz;
        #pragma unroll
        for (int kt = 0; kt < 4; kt++) {
            bf16x8 bw = *(const bf16x8*)(wf  + (nt * 4 + kt) * 512 + lane * 8);
            bf16x8 bd = *(const bf16x8*)(wfd + (nt * 4 + kt) * 512 + lane * 8);
            bf16x8 bs = *(const bf16x8*)(wfs + (nt * 4 + kt) * 512 + lane * 8);
            #pragma unroll
            for (int mt = 0; mt < 2; mt++) {
                rr[mt] = mfma16(ah[mt][kt], bw, rr[mt]);
                kd[mt] = mfma16(ah[mt][kt], bd, kd[mt]);
                ks[mt] = mfma16(ah[mt][kt], bs, ks[mt]);
            }
        }
        #pragma unroll
        for (int mt = 0; mt < 2; mt++) {
            int el = 8 * w + 4 * mt + q;
            f32x4 zA = mt ? zet1 : zet0;
            float et6[6] = {zA[0], zA[1], zA[2], zA[3],
                            mt ? zetB[2] : zetB[0], mt ? zetB[3] : zetB[1]};
            float o[4] = {rr[mt][0], rr[mt][1], rr[mt][2], rr[mt][3]};
            edge_update(o, kd[mt], ks[mt], et6);
            if (!LAST) {
                #pragma unroll
                for (int j = 0; j < 4; j++)
                    lA[swz128(32 * w + 16 * mt + 4 * q + j, col)] = (bf16_t)o[j];
            } else {
                lA[swz128(el, col)] = (bf16_t)(o[0] + o[1] + o[2] + o[3]);  // hg
            }
        }
    }
    __syncthreads();
}

__device__ __forceinline__ float ce_group(const float* p, const float* a, int off, int len) {
    float m = p[off];
    #pragma unroll
    for (int i = 1; i < 5; i++) if (i < len) m = fmaxf(m, p[off + i]);
    float am = a[off]; int lbl = 0;
    #pragma unroll
    for (int i = 1; i < 5; i++) if (i < len) { float av = a[off + i]; if (av > am) { am = av; lbl = i; } }
    float s = 0.f;
    #pragma unroll
    for (int i = 0; i < 5; i++) if (i < len) s += __expf(p[off + i] - m);
    return (m + __logf(s)) - p[off + lbl];
}

// ---------------------------------------------------------------------------
// Fully fused: conv0 -> conv1 -> conv2 -> readout -> VAE decoder -> loss.
// 32 elements (128 node rows) per block, 4 waves, 256 threads.
// ---------------------------------------------------------------------------
__global__ __launch_bounds__(256, 3) void fused_kernel(
    const float* __restrict__ x, const float* __restrict__ ea,
    const float* __restrict__ arch, const float* __restrict__ eps,
    const bf16_t* __restrict__ wfr, const float* __restrict__ bias,
    const float* __restrict__ fc3_b, const float* __restrict__ fc4_b,
    const float* __restrict__ fc5_b, const float* __restrict__ d1_mb,
    const float* __restrict__ d1_rb, const float* __restrict__ d2_mb,
    const float* __restrict__ d2_rb,
    float* __restrict__ ce_part, float* __restrict__ kld_part)
{
    __shared__ __align__(16) bf16_t lA[128 * 128];   // 32 KB, aliased by decoder
    __shared__ __align__(16) float  lred[8];         // tiny reduce scratch

    const int tid = threadIdx.x;
    const int w = tid >> 6, lane = tid & 63, q = lane >> 4, lr = lane & 15;
    const int e0 = blockIdx.x * 32;
    const int r0 = e0 * 4;

    // ---- build ea A-fragments once; rows permuted for lane-local et output ----
    bf16x8 aet[3];
    #pragma unroll
    for (int t = 0; t < 3; t++) {
        bf16x8 a = {0, 0, 0, 0, 0, 0, 0, 0};
        if (q == 0) {
            int el_w, u;
            if (t < 2) { el_w = 4 * t + (lr >> 2); u = lr & 3; }
            else       { el_w = 4 * ((lr >> 1) & 1) + (lr >> 2); u = 4 + (lr & 1); }
            const float* pe = ea + (size_t)((e0 + 8 * w + el_w) * 6 + u) * 5;
            #pragma unroll
            for (int i = 0; i < 5; i++) a[i] = (bf16_t)pe[i];
        }
        aet[t] = a;
    }

    // ---- conv0 as MFMA (K = 4 padded to 32): h0 = x@W0 + b0 + messages ----
    {
        bf16x8 ax[2];
        #pragma unroll
        for (int mt = 0; mt < 2; mt++) {
            float4 xv = {0.f, 0.f, 0.f, 0.f};
            if (q == 0) xv = *(const float4*)(x + (size_t)(r0 + 32 * w + 16 * mt + lr) * 4);
            bf16x8 a = {0, 0, 0, 0, 0, 0, 0, 0};
            a[0] = (bf16_t)xv.x; a[1] = (bf16_t)xv.y; a[2] = (bf16_t)xv.z; a[3] = (bf16_t)xv.w;
            ax[mt] = a;
        }
        const bf16_t* w0f = wfr + 320 * 512;
        const bf16_t* wdf = wfr + 328 * 512;
        const bf16_t* wsf = wfr + 336 * 512;
        const bf16_t* wef = wfr + 344 * 512;
        const float* b0 = bias + 256;
        float bv8[8];
        #pragma unroll
        for (int nt = 0; nt < 8; nt++) bv8[nt] = b0[16 * nt + lr];
        #pragma unroll 2
        for (int nt = 0; nt < 8; nt++) {
            int col = 16 * nt + lr;
            const f32x4 zz = {0.f, 0.f, 0.f, 0.f};
            bf16x8 be = *(const bf16x8*)(wef + nt * 512 + lane * 8);
            f32x4 zet0 = mfma16(aet[0], be, zz);
            f32x4 zet1 = mfma16(aet[1], be, zz);
            f32x4 zetB = mfma16(aet[2], be, zz);
            float bb = bv8[nt];
            f32x4 rr[2], kd[2], ks[2];
            rr[0] = (f32x4){bb, bb, bb, bb}; rr[1] = rr[0];
            kd[0] = zz; kd[1] = zz;
            ks[0] = zz; ks[1] = zz;
            bf16x8 bw0 = *(const bf16x8*)(w0f + nt * 512 + lane * 8);
            bf16x8 bwa = *(const bf16x8*)(wdf + nt * 512 + lane * 8);
            bf16x8 bwb = *(const bf16x8*)(wsf + nt * 512 + lane * 8);
            #pragma unroll
            for (int mt = 0; mt < 2; mt++) {
                rr[mt] = mfma16(ax[mt], bw0, rr[mt]);
                kd[mt] = mfma16(ax[mt], bwa, kd[mt]);
                ks[mt] = mfma16(ax[mt], bwb, ks[mt]);
            }
            #pragma unroll
            for (int mt = 0; mt < 2; mt++) {
                f32x4 zA = mt ? zet1 : zet0;
                float et6[6] = {zA[0], zA[1], zA[2], zA[3],
                                mt ? zetB[2] : zetB[0], mt ? zetB[3] : zetB[1]};
                float o[4] = {rr[mt][0], rr[mt][1], rr[mt][2], rr[mt][3]};
                edge_update(o, kd[mt], ks[mt], et6);
                #pragma unroll
                for (int j = 0; j < 4; j++)
                    lA[swz128(32 * w + 16 * mt + 4 * q + j, col)] = (bf16_t)o[j];
            }
        }
    }
    __syncthreads();

    // ---- conv1, conv2 (single-pass, W12-collapsed) ----
    conv_pass<false>(lA, aet, wfr,            wfr + 352 * 512, bias,       w, q, lr, lane);
    conv_pass<true >(lA, aet, wfr + 96 * 512, wfr + 360 * 512, bias + 128, w, q, lr, lane);
    // lA rows 0..31 now hold hg (swizzled)

    // ---- decoder: 32 elements = 2 m-tiles; wave w: mtd = w>>1, tp = w&1 ----
    const int mtd = w >> 1, tp = w & 1;
    const int grow = 16 * mtd + lr;

    // GEMM1: [mu|lv] = hg @ [fc3|fc4] + b
    bf16x8 ag[4];
    #pragma unroll
    for (int kt = 0; kt < 4; kt++)
        ag[kt] = *(const bf16x8*)(lA + grow * 128 + (((4 * kt + q) ^ (grow & 7)) << 3));
    float bmu = fc3_b[16 * tp + lr], blv = fc4_b[16 * tp + lr];
    f32x4 amu = (f32x4){bmu, bmu, bmu, bmu}, alv = (f32x4){blv, blv, blv, blv};
    const bf16_t* f3 = wfr + (192 + tp * 4) * 512;
    const bf16_t* f4 = wfr + (200 + tp * 4) * 512;
    #pragma unroll
    for (int kt = 0; kt < 4; kt++) {
        amu = mfma16(ag[kt], *(const bf16x8*)(f3 + kt * 512 + lane * 8), amu);
        alv = mfma16(ag[kt], *(const bf16x8*)(f4 + kt * 512 + lane * 8), alv);
    }
    float kldp = 0.f;
    bf16_t* lz = lA + 4096;               // bytes [8192,10240): z 32x32 bf16
    #pragma unroll
    for (int j = 0; j < 4; j++) {
        int el = 16 * mtd + 4 * q + j;
        float mu = amu[j], lv = alv[j];
        kldp += 1.f + lv - mu * mu - __expf(lv);
        int c = 16 * tp + lr;
        float zz2 = eps[(size_t)(e0 + el) * 32 + c] * 0.01f * __expf(0.5f * lv) + mu;
        lz[el * 32 + ((((c >> 3) ^ (el & 3)) << 3) | (c & 7))] = (bf16_t)zz2;
    }
    __syncthreads();

    // GEMM2: Hg = tanh(z @ fc5 + b)  (K=32)
    bf16_t* lHg = lA + 6144;              // bytes [12288,20480): Hg 32x128 bf16
    bf16x8 az = *(const bf16x8*)(lz + grow * 32 + ((q ^ (grow & 3)) << 3));
    const bf16_t* f5 = wfr + 208 * 512;
    #pragma unroll 2
    for (int i = 0; i < 4; i++) {
        int nt = 4 * tp + i;
        float b = fc5_b[16 * nt + lr];
        f32x4 a = (f32x4){b, b, b, b};
        a = mfma16(az, *(const bf16x8*)(f5 + nt * 512 + lane * 8), a);
        #pragma unroll
        for (int j = 0; j < 4; j++) {
            float ex2 = __expf(2.f * a[j]);
            float th = 1.f - 2.f / (ex2 + 1.f);
            lHg[swz128(16 * mtd + 4 * q + j, 16 * nt + lr)] = (bf16_t)th;
        }
    }
    __syncthreads();

    // GEMM3: h1 = lrelu(Hg@d1_mw+mb) + (Hg@d1_rw+rb) -> lA base (hg dead)
    bf16x8 aHg[4];
    #pragma unroll
    for (int kt = 0; kt < 4; kt++)
        aHg[kt] = *(const bf16x8*)(lHg + grow * 128 + (((4 * kt + q) ^ (grow & 7)) << 3));
    const bf16_t* wd1m = wfr + 216 * 512;
    const bf16_t* wd1r = wfr + 248 * 512;
    #pragma unroll 2
    for (int i = 0; i < 4; i++) {
        int nt = 4 * tp + i;
        int col = 16 * nt + lr;
        float bm = d1_mb[col], br = d1_rb[col];
        f32x4 am = (f32x4){bm, bm, bm, bm}, ar = (f32x4){br, br, br, br};
        #pragma unroll
        for (int kt = 0; kt < 4; kt++) {
            am = mfma16(aHg[kt], *(const bf16x8*)(wd1m + (nt * 4 + kt) * 512 + lane * 8), am);
            ar = mfma16(aHg[kt], *(const bf16x8*)(wd1r + (nt * 4 + kt) * 512 + lane * 8), ar);
        }
        #pragma unroll
        for (int j = 0; j < 4; j++) {
            float v = fmaxf(am[j], 0.01f * am[j]) + ar[j];
            lA[swz128(16 * mtd + 4 * q + j, col)] = (bf16_t)v;
        }
    }
    __syncthreads();

    // GEMM4: pred = lrelu(h1@d2_mw+mb) + (h1@d2_rw+rb), N=78 (pad 80)
    bf16x8 a1[4];
    #pragma unroll
    for (int kt = 0; kt < 4; kt++)
        a1[kt] = *(const bf16x8*)(lA + grow * 128 + (((4 * kt + q) ^ (grow & 7)) << 3));
    float* lpred = (float*)(lA + 10240);  // bytes [20480,30720): pred 32x80 f32
    const bf16_t* wd2m = wfr + 280 * 512;
    const bf16_t* wd2r = wfr + 300 * 512;
    const int ntbeg = tp ? 3 : 0, ntend = tp ? 5 : 3;
    #pragma unroll 2
    for (int nt = ntbeg; nt < ntend; nt++) {
        int col = 16 * nt + lr;
        float bm = (col < 78) ? d2_mb[col] : 0.f;
        float br = (col < 78) ? d2_rb[col] : 0.f;
        f32x4 pm = (f32x4){bm, bm, bm, bm}, pr = (f32x4){br, br, br, br};
        #pragma unroll
        for (int kt = 0; kt < 4; kt++) {
            pm = mfma16(a1[kt], *(const bf16x8*)(wd2m + (nt * 4 + kt) * 512 + lane * 8), pm);
            pr = mfma16(a1[kt], *(const bf16x8*)(wd2r + (nt * 4 + kt) * 512 + lane * 8), pr);
        }
        #pragma unroll
        for (int j = 0; j < 4; j++) {
            float v = fmaxf(pm[j], 0.01f * pm[j]) + pr[j];
            lpred[(16 * mtd + 4 * q + j) * 80 + col] = v;
        }
    }
    __syncthreads();

    // ---- CE loss: 32 elems x 6 slots = 192 tasks ----
    float ces = 0.f;
    if (tid < 192) {
        int el = tid / 6, u = tid - el * 6;
        const float* pa = arch + ((size_t)(e0 + el) * 6 + u) * 13;
        const float* pp = lpred + el * 80 + u * 13;
        ces  = ce_group(pp, pa, 0, 4);
        ces += ce_group(pp, pa, 4, 4);
        ces += ce_group(pp, pa, 8, 5);
    }
    // combined wave butterfly reduce (ce + kld), then 1 barrier
    #pragma unroll
    for (int m2 = 1; m2 < 64; m2 <<= 1) {
        ces  += __shfl_xor(ces, m2, 64);
        kldp += __shfl_xor(kldp, m2, 64);
    }
    if (lane == 0) { lred[w] = ces; lred[4 + w] = kldp; }
    __syncthreads();
    if (tid == 0) {
        ce_part[blockIdx.x]  = lred[0] + lred[1] + lred[2] + lred[3];
        kld_part[blockIdx.x] = lred[4] + lred[5] + lred[6] + lred[7];
    }
}

__global__ __launch_bounds__(256) void final_reduce(
    const float* __restrict__ ce_part, const float* __restrict__ kld_part,
    float* __restrict__ out)
{
    __shared__ float r[256];
    int tid = threadIdx.x;
    float c = 0.f, k = 0.f;
    for (int i = tid; i < 2048; i += 256) { c += ce_part[i]; k += kld_part[i]; }
    r[tid] = c; __syncthreads();
    for (int s = 128; s > 0; s >>= 1) { if (tid < s) r[tid] += r[tid + s]; __syncthreads(); }
    float ctot = r[0];
    __syncthreads();
    r[tid] = k; __syncthreads();
    for (int s = 128; s > 0; s >>= 1) { if (tid < s) r[tid] += r[tid + s]; __syncthreads(); }
    if (tid == 0) {
        float ktot = r[0];
        out[0] = ctot / (65536.f * 6.f) - 0.5f * 0.005f * (ktot / (65536.f * 32.f));
    }
}

// ---------------------------------------------------------------------------
extern "C" void kernel_launch(void* const* d_in, const int* in_sizes, int n_in,
                              void* d_out, int out_size, void* d_ws, size_t ws_size,
                              hipStream_t stream)
{
    const float* x      = (const float*)d_in[0];
    const float* ea     = (const float*)d_in[1];
    const float* arch   = (const float*)d_in[2];
    const float* eps    = (const float*)d_in[3];
    const float* c0_rw1 = (const float*)d_in[5];
    const float* c0_rb1 = (const float*)d_in[6];
    const float* c0_rw2 = (const float*)d_in[7];
    const float* c0_rb2 = (const float*)d_in[8];
    const float* c0_kw  = (const float*)d_in[9];
    const float* c1_rw1 = (const float*)d_in[10];
    const float* c1_rb1 = (const float*)d_in[11];
    const float* c1_rw2 = (const float*)d_in[12];
    const float* c1_rb2 = (const float*)d_in[13];
    const float* c1_kw  = (const float*)d_in[14];
    const float* c2_rw1 = (const float*)d_in[15];
    const float* c2_rb1 = (const float*)d_in[16];
    const float* c2_rw2 = (const float*)d_in[17];
    const float* c2_rb2 = (const float*)d_in[18];
    const float* c2_kw  = (const float*)d_in[19];
    const float* fc3_w  = (const float*)d_in[20];
    const float* fc3_b  = (const float*)d_in[21];
    const float* fc4_w  = (const float*)d_in[22];
    const float* fc4_b  = (const float*)d_in[23];
    const float* fc5_w  = (const float*)d_in[24];
    const float* fc5_b  = (const float*)d_in[25];
    const float* d1_mw  = (const float*)d_in[26];
    const float* d1_mb  = (const float*)d_in[27];
    const float* d1_rw  = (const float*)d_in[28];
    const float* d1_rb  = (const float*)d_in[29];
    const float* d2_mw  = (const float*)d_in[30];
    const float* d2_mb  = (const float*)d_in[31];
    const float* d2_rw  = (const float*)d_in[32];
    const float* d2_rb  = (const float*)d_in[33];

    bf16_t* wfr      = (bf16_t*)d_ws;                      // 368*512*2 = 376832 B
    float*  bias     = (float*)((char*)d_ws + 376832);     // 384 f32 = 1536 B
    float*  ce_part  = (float*)((char*)d_ws + 378368);     // 2048 f32
    float*  kld_part = (float*)((char*)d_ws + 386560);     // 2048 f32

    PrepSrcs ps;
    ps.p[0] = c1_kw;  ps.p[1] = c2_kw;  ps.p[2] = fc3_w;  ps.p[3] = fc4_w;
    ps.p[4] = fc5_w;  ps.p[5] = d1_mw;  ps.p[6] = d1_rw;  ps.p[7] = d2_mw;
    ps.p[8] = d2_rw;  ps.p[9] = c0_kw;  ps.p[10] = c1_rw1; ps.p[11] = c1_rw2;
    ps.p[12] = c2_rw1; ps.p[13] = c2_rw2; ps.p[14] = c0_rw1; ps.p[15] = c0_rw2;

    prep_weights<<<371, 256, 0, stream>>>(ps, c0_rb1, c0_rb2, c1_rb1, c1_rb2,
                                          c2_rb1, c2_rb2, wfr, bias);
    fused_kernel<<<BATCH / 32, 256, 0, stream>>>(
        x, ea, arch, eps, wfr, bias,
        fc3_b, fc4_b, fc5_b, d1_mb, d1_rb, d2_mb, d2_rb,
        ce_part, kld_part);
    final_reduce<<<1, 256, 0, stream>>>(ce_part, kld_part, (float*)d_out);
}

// Round 10
// 116.838 us; speedup vs baseline: 1.0952x; 1.0952x over previous
//
#include <hip/hip_runtime.h>
#include <hip/hip_bf16.h>

#define BATCH 65536

typedef __bf16 bf16_t;
typedef __bf16 bf16x8 __attribute__((ext_vector_type(8)));
typedef float  f32x4  __attribute__((ext_vector_type(4)));

__device__ __forceinline__ f32x4 mfma16(bf16x8 a, bf16x8 b, f32x4 c) {
    return __builtin_amdgcn_mfma_f32_16x16x32_bf16(a, b, c, 0, 0, 0);
}
// element index into a 128-col bf16 LDS tile, XOR-swizzled on 16B chunks
__device__ __forceinline__ int swz128(int row, int col) {
    return row * 128 + ((((col >> 3) ^ (row & 7)) << 3) | (col & 7));
}

// ---------------------------------------------------------------------------
// Weight prep: f32 weights -> pre-swizzled bf16 B-fragments.
// Fragment (nt,kt): lane l elem j holds W[32*kt + 8*(l>>4) + j][16*nt + (l&15)]
// at dst[fragIdx*512 + l*8 + j].
// Frag map (368 frags):
//   0   c1_W12 = c1_rw1@c1_rw2 (128x128, 32)
//   32  c1_kwd (c1_kw rows 0..127, 32)     64  c1_kws (rows 128..255, 32)
//   96  c2_W12 (32)   128 c2_kwd (32)   160 c2_kws (32)
//   192 fc3 (128x32, 8)   200 fc4 (8)   208 fc5 (32x128 K=32, 8)
//   216 d1_mw (32)  248 d1_rw (32)  280 d2_mw (128x78, 20)  300 d2_rw (20)
//   320 c0_W12 = c0_rw1@c0_rw2 (K pad 4->32, 8)
//   328 c0_kw dst rows 0..3 (8)   336 c0_kw src rows 4..7 (8)
//   344 c0_kwe rows 8..12 (8)  352 c1_kwe rows 256..260 (8)  360 c2_kwe (8)
// bias: [0:128) b12_c1 | [128:256) b12_c2 | [256:384) b0_c0
// ---------------------------------------------------------------------------
struct PrepSrcs { const float* p[16]; };

__global__ __launch_bounds__(256) void prep_weights(PrepSrcs ps,
    const float* __restrict__ c0_rb1, const float* __restrict__ c0_rb2,
    const float* __restrict__ c1_rb1, const float* __restrict__ c1_rb2,
    const float* __restrict__ c2_rb1, const float* __restrict__ c2_rb2,
    bf16_t* __restrict__ dst, float* __restrict__ bias)
{
    int f = blockIdx.x;
    if (f >= 368) {                       // bias blocks
        int c = threadIdx.x;
        if (c < 128) {
            if (f == 368) {               // b12_c1 = c1_rb1 @ c1_rw2 + c1_rb2
                const float* rw2 = ps.p[11];
                float s = c1_rb2[c];
                for (int m = 0; m < 128; m++) s += c1_rb1[m] * rw2[m * 128 + c];
                bias[c] = s;
            } else if (f == 369) {        // b12_c2
                const float* rw2 = ps.p[13];
                float s = c2_rb2[c];
                for (int m = 0; m < 128; m++) s += c2_rb1[m] * rw2[m * 128 + c];
                bias[128 + c] = s;
            } else {                      // b0 = c0_rb1 @ c0_rw2 + c0_rb2
                const float* rw2 = ps.p[15];
                float s = c0_rb2[c];
                for (int m = 0; m < 4; m++) s += c0_rb1[m] * rw2[m * 128 + c];
                bias[256 + c] = s;
            }
        }
        return;
    }
    const int BASE[20] = {0,32,64,96,128,160,192,200,208,216,248,280,300,320,328,336,344,352,360,368};
    const int SRC[19]  = {10,0,0,12,1,1,2,3,4,5,6,7,8,14,9,9,9,0,1};
    const int KTt[19]  = {4,4,4,4,4,4,4,4,1,4,4,4,4,1,1,1,1,1,1};
    const int KLIM[19] = {128,128,128,128,128,128,128,128,32,128,128,128,128,4,4,4,5,5,5};
    const int NLIM[19] = {128,128,128,128,128,128,32,32,128,128,128,78,78,128,128,128,128,128,128};
    const int STR[19]  = {128,128,128,128,128,128,32,32,128,128,128,78,78,128,128,128,128,128,128};
    const int RO[19]   = {0,0,128,0,0,128,0,0,0,0,0,0,0,0,0,4,8,256,256};

    int ei = 0;
    while (ei < 18 && BASE[ei + 1] <= f) ei++;
    int lf = f - BASE[ei];
    int kt = lf % KTt[ei];
    int nt = lf / KTt[ei];
    #pragma unroll
    for (int r2 = 0; r2 < 2; r2++) {
        int idx = threadIdx.x * 2 + r2;
        int l = idx >> 3, j = idx & 7;
        int row = 32 * kt + 8 * (l >> 4) + j;
        int col = 16 * nt + (l & 15);
        float v = 0.f;
        if (ei == 0 || ei == 3) {         // W12 = rw1 @ rw2, K=128
            const float* rw1 = ps.p[ei == 0 ? 10 : 12];
            const float* rw2 = ps.p[ei == 0 ? 11 : 13];
            for (int m = 0; m < 128; m++) v += rw1[row * 128 + m] * rw2[m * 128 + col];
        } else if (ei == 13) {            // c0_W12, K=4 (rows >=4 zero)
            if (row < 4) {
                const float* rw1 = ps.p[14];
                const float* rw2 = ps.p[15];
                for (int m = 0; m < 4; m++) v += rw1[row * 4 + m] * rw2[m * 128 + col];
            }
        } else {
            if (row < KLIM[ei] && col < NLIM[ei])
                v = ps.p[SRC[ei]][(row + RO[ei]) * STR[ei] + col];
        }
        dst[f * 512 + idx] = (bf16_t)v;
    }
}

// ---------------------------------------------------------------------------
// Per-lane message assembly. edges: src {0,0,1,0,1,2} dst {1,2,2,3,3,3}
// ---------------------------------------------------------------------------
__device__ __forceinline__ void edge_update(float o[4], const f32x4& kd, const f32x4& ks,
                                            const float* et)
{
    float mm;
    mm = kd[1] + ks[0] + et[0]; mm = fmaxf(mm, 0.01f * mm); o[1] += mm;
    mm = kd[2] + ks[0] + et[1]; mm = fmaxf(mm, 0.01f * mm); o[2] += mm;
    mm = kd[2] + ks[1] + et[2]; mm = fmaxf(mm, 0.01f * mm); o[2] += mm;
    mm = kd[3] + ks[0] + et[3]; mm = fmaxf(mm, 0.01f * mm); o[3] += mm;
    mm = kd[3] + ks[1] + et[4]; mm = fmaxf(mm, 0.01f * mm); o[3] += mm;
    mm = kd[3] + ks[2] + et[5]; mm = fmaxf(mm, 0.01f * mm); o[3] += mm;
}

// ---------------------------------------------------------------------------
// et via lane-local MFMA output (no LDS round-trip).
// A-row permutation chosen so C rows land in the consuming lane:
//   aet[0] (mt=0) / aet[1] (mt=1): row 4*q_el + u  -> lane q_el, reg u   (u=0..3)
//   aet[2] (both mt):  row 4*q_el + 2*mt_el + (u-4) -> lane q_el, reg 2*mt+(u-4)
// ---------------------------------------------------------------------------

// ---------------------------------------------------------------------------
// Single-pass conv layer (resid collapsed into W12): out = h@W12 + b12 + msgs.
// LAST: write hg (sum of 4 node rows) into lA rows 0..31.
// ---------------------------------------------------------------------------
template<bool LAST>
__device__ __forceinline__ void conv_pass(
    bf16_t* lA, const bf16x8 aet[3],
    const bf16_t* wf, const bf16_t* wet, const float* b12,
    int w, int q, int lr, int lane)
{
    bf16x8 ah[2][4];
    #pragma unroll
    for (int mt = 0; mt < 2; mt++) {
        int row = 32 * w + 16 * mt + lr;
        #pragma unroll
        for (int kt = 0; kt < 4; kt++)
            ah[mt][kt] = *(const bf16x8*)(lA + row * 128 + (((4 * kt + q) ^ (row & 7)) << 3));
    }
    __syncthreads();                      // all reads done; lA may be overwritten

    const bf16_t* wfd = wf + 32 * 512;
    const bf16_t* wfs = wf + 64 * 512;
    #pragma unroll 2
    for (int nt = 0; nt < 8; nt++) {
        int col = 16 * nt + lr;
        const f32x4 zz = {0.f, 0.f, 0.f, 0.f};
        bf16x8 be = *(const bf16x8*)(wet + nt * 512 + lane * 8);
        f32x4 zet0 = mfma16(aet[0], be, zz);
        f32x4 zet1 = mfma16(aet[1], be, zz);
        f32x4 zetB = mfma16(aet[2], be, zz);
        float bv = b12[col];
        f32x4 rr[2], kd[2], ks[2];
        rr[0] = (f32x4){bv, bv, bv, bv}; rr[1] = rr[0];
        kd[0] = zz; kd[1] = zz;
        ks[0] = zz; ks[1] = zz;
        #pragma unroll
        for (int kt = 0; kt < 4; kt++) {
            bf16x8 bw = *(const bf16x8*)(wf  + (nt * 4 + kt) * 512 + lane * 8);
            bf16x8 bd = *(const bf16x8*)(wfd + (nt * 4 + kt) * 512 + lane * 8);
            bf16x8 bs = *(const bf16x8*)(wfs + (nt * 4 + kt) * 512 + lane * 8);
            #pragma unroll
            for (int mt = 0; mt < 2; mt++) {
                rr[mt] = mfma16(ah[mt][kt], bw, rr[mt]);
                kd[mt] = mfma16(ah[mt][kt], bd, kd[mt]);
                ks[mt] = mfma16(ah[mt][kt], bs, ks[mt]);
            }
        }
        #pragma unroll
        for (int mt = 0; mt < 2; mt++) {
            int el = 8 * w + 4 * mt + q;
            f32x4 zA = mt ? zet1 : zet0;
            float et6[6] = {zA[0], zA[1], zA[2], zA[3],
                            mt ? zetB[2] : zetB[0], mt ? zetB[3] : zetB[1]};
            float o[4] = {rr[mt][0], rr[mt][1], rr[mt][2], rr[mt][3]};
            edge_update(o, kd[mt], ks[mt], et6);
            if (!LAST) {
                #pragma unroll
                for (int j = 0; j < 4; j++)
                    lA[swz128(32 * w + 16 * mt + 4 * q + j, col)] = (bf16_t)o[j];
            } else {
                lA[swz128(el, col)] = (bf16_t)(o[0] + o[1] + o[2] + o[3]);  // hg
            }
        }
    }
    __syncthreads();
}

__device__ __forceinline__ float ce_group(const float* p, const float* a, int off, int len) {
    float m = p[off];
    #pragma unroll
    for (int i = 1; i < 5; i++) if (i < len) m = fmaxf(m, p[off + i]);
    float am = a[off]; int lbl = 0;
    #pragma unroll
    for (int i = 1; i < 5; i++) if (i < len) { float av = a[off + i]; if (av > am) { am = av; lbl = i; } }
    float s = 0.f;
    #pragma unroll
    for (int i = 0; i < 5; i++) if (i < len) s += __expf(p[off + i] - m);
    return (m + __logf(s)) - p[off + lbl];
}

// ---------------------------------------------------------------------------
// Fully fused: conv0 -> conv1 -> conv2 -> readout -> VAE decoder -> loss.
// 32 elements (128 node rows) per block, 4 waves, 256 threads.
// LDS is EXACTLY 32 KiB (lred aliased into dead lA space) -> 5 blocks/CU.
// ---------------------------------------------------------------------------
__global__ __launch_bounds__(256, 4) void fused_kernel(
    const float* __restrict__ x, const float* __restrict__ ea,
    const float* __restrict__ arch, const float* __restrict__ eps,
    const bf16_t* __restrict__ wfr, const float* __restrict__ bias,
    const float* __restrict__ fc3_b, const float* __restrict__ fc4_b,
    const float* __restrict__ fc5_b, const float* __restrict__ d1_mb,
    const float* __restrict__ d1_rb, const float* __restrict__ d2_mb,
    const float* __restrict__ d2_rb,
    float* __restrict__ ce_part, float* __restrict__ kld_part)
{
    __shared__ __align__(16) bf16_t lA[128 * 128];   // 32 KB exactly; heavily aliased

    const int tid = threadIdx.x;
    const int w = tid >> 6, lane = tid & 63, q = lane >> 4, lr = lane & 15;
    const int e0 = blockIdx.x * 32;
    const int r0 = e0 * 4;

    // ---- build ea A-fragments once; rows permuted for lane-local et output ----
    bf16x8 aet[3];
    #pragma unroll
    for (int t = 0; t < 3; t++) {
        bf16x8 a = {0, 0, 0, 0, 0, 0, 0, 0};
        if (q == 0) {
            int el_w, u;
            if (t < 2) { el_w = 4 * t + (lr >> 2); u = lr & 3; }
            else       { el_w = 4 * ((lr >> 1) & 1) + (lr >> 2); u = 4 + (lr & 1); }
            const float* pe = ea + (size_t)((e0 + 8 * w + el_w) * 6 + u) * 5;
            #pragma unroll
            for (int i = 0; i < 5; i++) a[i] = (bf16_t)pe[i];
        }
        aet[t] = a;
    }

    // ---- conv0 as MFMA (K = 4 padded to 32): h0 = x@W0 + b0 + messages ----
    {
        bf16x8 ax[2];
        #pragma unroll
        for (int mt = 0; mt < 2; mt++) {
            float4 xv = {0.f, 0.f, 0.f, 0.f};
            if (q == 0) xv = *(const float4*)(x + (size_t)(r0 + 32 * w + 16 * mt + lr) * 4);
            bf16x8 a = {0, 0, 0, 0, 0, 0, 0, 0};
            a[0] = (bf16_t)xv.x; a[1] = (bf16_t)xv.y; a[2] = (bf16_t)xv.z; a[3] = (bf16_t)xv.w;
            ax[mt] = a;
        }
        const bf16_t* w0f = wfr + 320 * 512;
        const bf16_t* wdf = wfr + 328 * 512;
        const bf16_t* wsf = wfr + 336 * 512;
        const bf16_t* wef = wfr + 344 * 512;
        const float* b0 = bias + 256;
        #pragma unroll 2
        for (int nt = 0; nt < 8; nt++) {
            int col = 16 * nt + lr;
            const f32x4 zz = {0.f, 0.f, 0.f, 0.f};
            bf16x8 be = *(const bf16x8*)(wef + nt * 512 + lane * 8);
            f32x4 zet0 = mfma16(aet[0], be, zz);
            f32x4 zet1 = mfma16(aet[1], be, zz);
            f32x4 zetB = mfma16(aet[2], be, zz);
            float bb = b0[col];
            f32x4 rr[2], kd[2], ks[2];
            rr[0] = (f32x4){bb, bb, bb, bb}; rr[1] = rr[0];
            kd[0] = zz; kd[1] = zz;
            ks[0] = zz; ks[1] = zz;
            bf16x8 bw0 = *(const bf16x8*)(w0f + nt * 512 + lane * 8);
            bf16x8 bwa = *(const bf16x8*)(wdf + nt * 512 + lane * 8);
            bf16x8 bwb = *(const bf16x8*)(wsf + nt * 512 + lane * 8);
            #pragma unroll
            for (int mt = 0; mt < 2; mt++) {
                rr[mt] = mfma16(ax[mt], bw0, rr[mt]);
                kd[mt] = mfma16(ax[mt], bwa, kd[mt]);
                ks[mt] = mfma16(ax[mt], bwb, ks[mt]);
            }
            #pragma unroll
            for (int mt = 0; mt < 2; mt++) {
                f32x4 zA = mt ? zet1 : zet0;
                float et6[6] = {zA[0], zA[1], zA[2], zA[3],
                                mt ? zetB[2] : zetB[0], mt ? zetB[3] : zetB[1]};
                float o[4] = {rr[mt][0], rr[mt][1], rr[mt][2], rr[mt][3]};
                edge_update(o, kd[mt], ks[mt], et6);
                #pragma unroll
                for (int j = 0; j < 4; j++)
                    lA[swz128(32 * w + 16 * mt + 4 * q + j, col)] = (bf16_t)o[j];
            }
        }
    }
    __syncthreads();

    // ---- conv1, conv2 (single-pass, W12-collapsed) ----
    conv_pass<false>(lA, aet, wfr,            wfr + 352 * 512, bias,       w, q, lr, lane);
    conv_pass<true >(lA, aet, wfr + 96 * 512, wfr + 360 * 512, bias + 128, w, q, lr, lane);
    // lA rows 0..31 now hold hg (swizzled)

    // ---- decoder: 32 elements = 2 m-tiles; wave w: mtd = w>>1, tp = w&1 ----
    const int mtd = w >> 1, tp = w & 1;
    const int grow = 16 * mtd + lr;

    // GEMM1: [mu|lv] = hg @ [fc3|fc4] + b
    bf16x8 ag[4];
    #pragma unroll
    for (int kt = 0; kt < 4; kt++)
        ag[kt] = *(const bf16x8*)(lA + grow * 128 + (((4 * kt + q) ^ (grow & 7)) << 3));
    float bmu = fc3_b[16 * tp + lr], blv = fc4_b[16 * tp + lr];
    f32x4 amu = (f32x4){bmu, bmu, bmu, bmu}, alv = (f32x4){blv, blv, blv, blv};
    const bf16_t* f3 = wfr + (192 + tp * 4) * 512;
    const bf16_t* f4 = wfr + (200 + tp * 4) * 512;
    #pragma unroll
    for (int kt = 0; kt < 4; kt++) {
        amu = mfma16(ag[kt], *(const bf16x8*)(f3 + kt * 512 + lane * 8), amu);
        alv = mfma16(ag[kt], *(const bf16x8*)(f4 + kt * 512 + lane * 8), alv);
    }
    float kldp = 0.f;
    bf16_t* lz = lA + 4096;               // bytes [8192,10240): z 32x32 bf16
    #pragma unroll
    for (int j = 0; j < 4; j++) {
        int el = 16 * mtd + 4 * q + j;
        float mu = amu[j], lv = alv[j];
        kldp += 1.f + lv - mu * mu - __expf(lv);
        int c = 16 * tp + lr;
        float zz2 = eps[(size_t)(e0 + el) * 32 + c] * 0.01f * __expf(0.5f * lv) + mu;
        lz[el * 32 + ((((c >> 3) ^ (el & 3)) << 3) | (c & 7))] = (bf16_t)zz2;
    }
    __syncthreads();

    // GEMM2: Hg = tanh(z @ fc5 + b)  (K=32)
    bf16_t* lHg = lA + 6144;              // bytes [12288,20480): Hg 32x128 bf16
    bf16x8 az = *(const bf16x8*)(lz + grow * 32 + ((q ^ (grow & 3)) << 3));
    const bf16_t* f5 = wfr + 208 * 512;
    #pragma unroll 1
    for (int i = 0; i < 4; i++) {
        int nt = 4 * tp + i;
        float b = fc5_b[16 * nt + lr];
        f32x4 a = (f32x4){b, b, b, b};
        a = mfma16(az, *(const bf16x8*)(f5 + nt * 512 + lane * 8), a);
        #pragma unroll
        for (int j = 0; j < 4; j++) {
            float ex2 = __expf(2.f * a[j]);
            float th = 1.f - 2.f / (ex2 + 1.f);
            lHg[swz128(16 * mtd + 4 * q + j, 16 * nt + lr)] = (bf16_t)th;
        }
    }
    __syncthreads();

    // GEMM3: h1 = lrelu(Hg@d1_mw+mb) + (Hg@d1_rw+rb) -> lA base (hg dead)
    bf16x8 aHg[4];
    #pragma unroll
    for (int kt = 0; kt < 4; kt++)
        aHg[kt] = *(const bf16x8*)(lHg + grow * 128 + (((4 * kt + q) ^ (grow & 7)) << 3));
    const bf16_t* wd1m = wfr + 216 * 512;
    const bf16_t* wd1r = wfr + 248 * 512;
    #pragma unroll 1
    for (int i = 0; i < 4; i++) {
        int nt = 4 * tp + i;
        int col = 16 * nt + lr;
        float bm = d1_mb[col], br = d1_rb[col];
        f32x4 am = (f32x4){bm, bm, bm, bm}, ar = (f32x4){br, br, br, br};
        #pragma unroll
        for (int kt = 0; kt < 4; kt++) {
            am = mfma16(aHg[kt], *(const bf16x8*)(wd1m + (nt * 4 + kt) * 512 + lane * 8), am);
            ar = mfma16(aHg[kt], *(const bf16x8*)(wd1r + (nt * 4 + kt) * 512 + lane * 8), ar);
        }
        #pragma unroll
        for (int j = 0; j < 4; j++) {
            float v = fmaxf(am[j], 0.01f * am[j]) + ar[j];
            lA[swz128(16 * mtd + 4 * q + j, col)] = (bf16_t)v;
        }
    }
    __syncthreads();

    // GEMM4: pred = lrelu(h1@d2_mw+mb) + (h1@d2_rw+rb), N=78 (pad 80)
    bf16x8 a1[4];
    #pragma unroll
    for (int kt = 0; kt < 4; kt++)
        a1[kt] = *(const bf16x8*)(lA + grow * 128 + (((4 * kt + q) ^ (grow & 7)) << 3));
    float* lpred = (float*)(lA + 10240);  // bytes [20480,30720): pred 32x80 f32
    const bf16_t* wd2m = wfr + 280 * 512;
    const bf16_t* wd2r = wfr + 300 * 512;
    const int ntbeg = tp ? 3 : 0, ntend = tp ? 5 : 3;
    #pragma unroll 1
    for (int nt = ntbeg; nt < ntend; nt++) {
        int col = 16 * nt + lr;
        float bm = (col < 78) ? d2_mb[col] : 0.f;
        float br = (col < 78) ? d2_rb[col] : 0.f;
        f32x4 pm = (f32x4){bm, bm, bm, bm}, pr = (f32x4){br, br, br, br};
        #pragma unroll
        for (int kt = 0; kt < 4; kt++) {
            pm = mfma16(a1[kt], *(const bf16x8*)(wd2m + (nt * 4 + kt) * 512 + lane * 8), pm);
            pr = mfma16(a1[kt], *(const bf16x8*)(wd2r + (nt * 4 + kt) * 512 + lane * 8), pr);
        }
        #pragma unroll
        for (int j = 0; j < 4; j++) {
            float v = fmaxf(pm[j], 0.01f * pm[j]) + pr[j];
            lpred[(16 * mtd + 4 * q + j) * 80 + col] = v;
        }
    }
    __syncthreads();

    // ---- CE loss: 32 elems x 6 slots = 192 tasks ----
    float ces = 0.f;
    if (tid < 192) {
        int el = tid / 6, u = tid - el * 6;
        const float* pa = arch + ((size_t)(e0 + el) * 6 + u) * 13;
        const float* pp = lpred + el * 80 + u * 13;
        ces  = ce_group(pp, pa, 0, 4);
        ces += ce_group(pp, pa, 4, 4);
        ces += ce_group(pp, pa, 8, 5);
    }
    // combined wave butterfly reduce (ce + kld), then 1 barrier
    #pragma unroll
    for (int m2 = 1; m2 < 64; m2 <<= 1) {
        ces  += __shfl_xor(ces, m2, 64);
        kldp += __shfl_xor(kldp, m2, 64);
    }
    // lred aliased into lA bytes [30720,30752) — after lpred, all else dead
    float* lred = (float*)(lA + 15360);
    if (lane == 0) { lred[w] = ces; lred[4 + w] = kldp; }
    __syncthreads();
    if (tid == 0) {
        ce_part[blockIdx.x]  = lred[0] + lred[1] + lred[2] + lred[3];
        kld_part[blockIdx.x] = lred[4] + lred[5] + lred[6] + lred[7];
    }
}

__global__ __launch_bounds__(256) void final_reduce(
    const float* __restrict__ ce_part, const float* __restrict__ kld_part,
    float* __restrict__ out)
{
    __shared__ float r[256];
    int tid = threadIdx.x;
    float c = 0.f, k = 0.f;
    for (int i = tid; i < 2048; i += 256) { c += ce_part[i]; k += kld_part[i]; }
    r[tid] = c; __syncthreads();
    for (int s = 128; s > 0; s >>= 1) { if (tid < s) r[tid] += r[tid + s]; __syncthreads(); }
    float ctot = r[0];
    __syncthreads();
    r[tid] = k; __syncthreads();
    for (int s = 128; s > 0; s >>= 1) { if (tid < s) r[tid] += r[tid + s]; __syncthreads(); }
    if (tid == 0) {
        float ktot = r[0];
        out[0] = ctot / (65536.f * 6.f) - 0.5f * 0.005f * (ktot / (65536.f * 32.f));
    }
}

// ---------------------------------------------------------------------------
extern "C" void kernel_launch(void* const* d_in, const int* in_sizes, int n_in,
                              void* d_out, int out_size, void* d_ws, size_t ws_size,
                              hipStream_t stream)
{
    const float* x      = (const float*)d_in[0];
    const float* ea     = (const float*)d_in[1];
    const float* arch   = (const float*)d_in[2];
    const float* eps    = (const float*)d_in[3];
    const float* c0_rw1 = (const float*)d_in[5];
    const float* c0_rb1 = (const float*)d_in[6];
    const float* c0_rw2 = (const float*)d_in[7];
    const float* c0_rb2 = (const float*)d_in[8];
    const float* c0_kw  = (const float*)d_in[9];
    const float* c1_rw1 = (const float*)d_in[10];
    const float* c1_rb1 = (const float*)d_in[11];
    const float* c1_rw2 = (const float*)d_in[12];
    const float* c1_rb2 = (const float*)d_in[13];
    const float* c1_kw  = (const float*)d_in[14];
    const float* c2_rw1 = (const float*)d_in[15];
    const float* c2_rb1 = (const float*)d_in[16];
    const float* c2_rw2 = (const float*)d_in[17];
    const float* c2_rb2 = (const float*)d_in[18];
    const float* c2_kw  = (const float*)d_in[19];
    const float* fc3_w  = (const float*)d_in[20];
    const float* fc3_b  = (const float*)d_in[21];
    const float* fc4_w  = (const float*)d_in[22];
    const float* fc4_b  = (const float*)d_in[23];
    const float* fc5_w  = (const float*)d_in[24];
    const float* fc5_b  = (const float*)d_in[25];
    const float* d1_mw  = (const float*)d_in[26];
    const float* d1_mb  = (const float*)d_in[27];
    const float* d1_rw  = (const float*)d_in[28];
    const float* d1_rb  = (const float*)d_in[29];
    const float* d2_mw  = (const float*)d_in[30];
    const float* d2_mb  = (const float*)d_in[31];
    const float* d2_rw  = (const float*)d_in[32];
    const float* d2_rb  = (const float*)d_in[33];

    bf16_t* wfr      = (bf16_t*)d_ws;                      // 368*512*2 = 376832 B
    float*  bias     = (float*)((char*)d_ws + 376832);     // 384 f32 = 1536 B
    float*  ce_part  = (float*)((char*)d_ws + 378368);     // 2048 f32
    float*  kld_part = (float*)((char*)d_ws + 386560);     // 2048 f32

    PrepSrcs ps;
    ps.p[0] = c1_kw;  ps.p[1] = c2_kw;  ps.p[2] = fc3_w;  ps.p[3] = fc4_w;
    ps.p[4] = fc5_w;  ps.p[5] = d1_mw;  ps.p[6] = d1_rw;  ps.p[7] = d2_mw;
    ps.p[8] = d2_rw;  ps.p[9] = c0_kw;  ps.p[10] = c1_rw1; ps.p[11] = c1_rw2;
    ps.p[12] = c2_rw1; ps.p[13] = c2_rw2; ps.p[14] = c0_rw1; ps.p[15] = c0_rw2;

    prep_weights<<<371, 256, 0, stream>>>(ps, c0_rb1, c0_rb2, c1_rb1, c1_rb2,
                                          c2_rb1, c2_rb2, wfr, bias);
    fused_kernel<<<BATCH / 32, 256, 0, stream>>>(
        x, ea, arch, eps, wfr, bias,
        fc3_b, fc4_b, fc5_b, d1_mb, d1_rb, d2_mb, d2_rb,
        ce_part, kld_part);
    final_reduce<<<1, 256, 0, stream>>>(ce_part, kld_part, (float*)d_out);
}